// Round 1
// baseline (10852.961 us; speedup 1.0000x reference)
//
#include <hip/hip_runtime.h>
#include <hip/hip_bf16.h>
#include <math.h>

#define DEVI __device__ __forceinline__

constexpr int B = 32, S = 64, T = 64, H = 512, V = 32000;
constexpr int G3 = 3 * H;     // 1536
constexpr int BT = B * T;     // 2048

// ---- workspace layout (in floats) ----
constexpr size_t UAK_OFF    = 0;                         // [B*S*H]   1,048,576
constexpr size_t GIE_OFF    = 1048576;                   // [B*T*G3]  3,145,728
constexpr size_t HALL_OFF   = 4194304;                   // [(T+1)*B*H] 1,064,960
constexpr size_t QBUF_OFF   = 5259264;                   // [B*H]
constexpr size_t CTX_OFF    = 5275648;                   // [B*H]
constexpr size_t BAR_OFF    = 5292032;                   // 64 ints
constexpr size_t ROWIDX_OFF = 5292096;                   // 2048 ints
constexpr size_t HBF_OFF    = 5294144;                   // bf16 [B*T*H] = 524,288 floats
constexpr size_t OWBF_OFF   = 5818432;                   // bf16 [V*H]  = 8,192,000 floats

typedef __attribute__((ext_vector_type(8))) short bf16x8;
typedef __attribute__((ext_vector_type(4))) float f32x4;

// -------------------- init: h0, barrier, token row indices --------------------
__global__ void k_init(const float* __restrict__ eh, const int* __restrict__ tgt,
                       float* __restrict__ ws) {
  int i = blockIdx.x * 256 + threadIdx.x;      // grid 64*256 = 16384
  if (i < B * H) ws[HALL_OFF + i] = eh[i];
  if (i < 64) ((int*)(ws + BAR_OFF))[i] = 0;
  if (i < BT) {
    int b = i / T, t = i % T;
    ((int*)(ws + ROWIDX_OFF))[i] = (t == 0) ? 0 : tgt[b * T + t - 1];
  }
}

// -------------------- out_w fp32 -> bf16 --------------------
__global__ void k_conv_outw(const float* __restrict__ w, ushort* __restrict__ o, int n4) {
  int i = blockIdx.x * blockDim.x + threadIdx.x;
  if (i < n4) {
    float4 v = *(const float4*)&w[(size_t)i * 4];
    ushort4 u;
    __hip_bfloat16 h0 = __float2bfloat16(v.x); u.x = *(ushort*)&h0;
    __hip_bfloat16 h1 = __float2bfloat16(v.y); u.y = *(ushort*)&h1;
    __hip_bfloat16 h2 = __float2bfloat16(v.z); u.z = *(ushort*)&h2;
    __hip_bfloat16 h3 = __float2bfloat16(v.w); u.w = *(ushort*)&h3;
    *(ushort4*)&o[(size_t)i * 4] = u;
  }
}

// -------- generic fp32 tiled GEMM: C[m,n] = A[arow(m),0:512] . Bw[n*ldb+0:512] + bias[n] --------
__global__ __launch_bounds__(256) void k_gemm_at(
    const float* __restrict__ A, const float* __restrict__ Bw, int ldb,
    const float* __restrict__ bias, float* __restrict__ C,
    const int* __restrict__ rowidx, int N) {
  __shared__ float As[64][36];
  __shared__ float Bs[64][36];
  int tid = threadIdx.x;
  int bm = blockIdx.x, bn = blockIdx.y;
  int tr = tid >> 4, tc = tid & 15;
  float acc[4][4] = {};
  for (int k0 = 0; k0 < 512; k0 += 32) {
    __syncthreads();
#pragma unroll
    for (int i = 0; i < 2; i++) {
      int e = tid + i * 256;              // 512 float4 slots
      int row = e >> 3, c4 = (e & 7) * 4;
      int ar = bm * 64 + row;
      int arow = rowidx ? rowidx[ar] : ar;
      float4 v = *(const float4*)&A[(size_t)arow * 512 + k0 + c4];
      *(float4*)&As[row][c4] = v;
      int br = bn * 64 + row;
      float4 u = *(const float4*)&Bw[(size_t)br * ldb + k0 + c4];
      *(float4*)&Bs[row][c4] = u;
    }
    __syncthreads();
#pragma unroll
    for (int kk = 0; kk < 32; kk++) {
      float av[4], bv[4];
#pragma unroll
      for (int i = 0; i < 4; i++) av[i] = As[tr * 4 + i][kk];
#pragma unroll
      for (int j = 0; j < 4; j++) bv[j] = Bs[tc * 4 + j][kk];
#pragma unroll
      for (int i = 0; i < 4; i++)
#pragma unroll
        for (int j = 0; j < 4; j++) acc[i][j] += av[i] * bv[j];
    }
  }
#pragma unroll
  for (int i = 0; i < 4; i++) {
    int m = bm * 64 + tr * 4 + i;
#pragma unroll
    for (int j = 0; j < 4; j++) {
      int n = bn * 64 + tc * 4 + j;
      C[(size_t)m * N + n] = acc[i][j] + bias[n];
    }
  }
}

// -------------------- device-scope grid barrier --------------------
DEVI void gridbar(int* bar, int nwg) {
  __syncthreads();
  if (threadIdx.x == 0) {
    __threadfence();
    int g = __hip_atomic_load(&bar[1], __ATOMIC_RELAXED, __HIP_MEMORY_SCOPE_AGENT);
    int old = __hip_atomic_fetch_add(&bar[0], 1, __ATOMIC_ACQ_REL, __HIP_MEMORY_SCOPE_AGENT);
    if (old == nwg - 1) {
      __hip_atomic_store(&bar[0], 0, __ATOMIC_RELAXED, __HIP_MEMORY_SCOPE_AGENT);
      __hip_atomic_store(&bar[1], g + 1, __ATOMIC_RELEASE, __HIP_MEMORY_SCOPE_AGENT);
    } else {
      while (__hip_atomic_load(&bar[1], __ATOMIC_ACQUIRE, __HIP_MEMORY_SCOPE_AGENT) == g)
        __builtin_amdgcn_s_sleep(1);
    }
    __threadfence();
  }
  __syncthreads();
}

// -------------------- persistent recurrence kernel --------------------
// grid = 256 WGs x 512 threads, 1 WG/CU. WG w owns h-columns {2w, 2w+1}.
__global__ __launch_bounds__(512, 1) void k_recur(
    const float* __restrict__ keys,
    const float* __restrict__ Wa_w, const float* __restrict__ Wa_b,
    const float* __restrict__ Va_w, const float* __restrict__ Va_b,
    const float* __restrict__ W_ih, const float* __restrict__ W_hh,
    const float* __restrict__ b_hh,
    float* __restrict__ ws, float* __restrict__ attn_out) {
  const int w = blockIdx.x;
  const int tid = threadIdx.x;
  float* UAK = ws + UAK_OFF;
  float* GIE = ws + GIE_OFF;
  float* HALL = ws + HALL_OFF;
  float* QB = ws + QBUF_OFF;
  float* CTX = ws + CTX_OFF;
  int* bar = (int*)(ws + BAR_OFF);
  __hip_bfloat16* HBF = (__hip_bfloat16*)(ws + HBF_OFF);

  __shared__ float sWcat[6][1028];   // rows: lj*3+g, cols 0:512 = W_ih ctx part, 512:1024 = W_hh
  __shared__ float sWa[2][512];
  __shared__ float sVa[512];
  __shared__ float sQ[512];
  __shared__ float sSc[64];
  __shared__ float red[64][8];
  __shared__ float red3[3][64][8];

  const int jh0 = 2 * w;
  for (int r = 0; r < 6; r++) {
    int lj = r / 3, g = r % 3;
    int jorig = g * 512 + jh0 + lj;
    for (int c = tid; c < 1024; c += 512) {
      float v = (c < 512) ? W_ih[(size_t)jorig * 1024 + 512 + c]
                          : W_hh[(size_t)jorig * 512 + (c - 512)];
      sWcat[r][c] = v;
    }
  }
  for (int c = tid; c < 1024; c += 512)
    sWa[c >> 9][c & 511] = Wa_w[(size_t)(jh0 + (c >> 9)) * 512 + (c & 511)];
  if (tid < 512) sVa[tid] = Va_w[tid];
  __syncthreads();

  const float va_b = Va_b[0];
  const int bb = w >> 3, sl = w & 7;

  for (int t = 0; t < T; t++) {
    const float* hcur = HALL + (size_t)t * B * H;
    // ---- Phase A1: q[b, jh0+lj] = h[b] . Wa[jh0+lj] + Wa_b ----
    {
      int c = tid >> 3, slice = tid & 7;   // c = b*2+lj
      int b = c >> 1, lj = c & 1;
      const float* hv = hcur + b * H + slice * 64;
      const float* wv = &sWa[lj][slice * 64];
      float acc = 0.f;
#pragma unroll
      for (int i = 0; i < 64; i += 4) {
        float4 h4 = *(const float4*)&hv[i];
        acc += h4.x * wv[i] + h4.y * wv[i + 1] + h4.z * wv[i + 2] + h4.w * wv[i + 3];
      }
      red[c][slice] = acc;
      __syncthreads();
      if (tid < 64) {
        int b2 = tid >> 1, lj2 = tid & 1;
        float s = 0.f;
#pragma unroll
        for (int i = 0; i < 8; i++) s += red[tid][i];
        QB[b2 * H + jh0 + lj2] = s + Wa_b[jh0 + lj2];
      }
    }
    gridbar(bar, gridDim.x);
    // ---- Phase A2: scores/softmax/ctx for b = bb (8 WGs per b, redundant scores) ----
    {
      sQ[tid] = QB[bb * H + tid];
      __syncthreads();
      int s = tid >> 3, slice = tid & 7;
      const float* uk = UAK + ((size_t)(bb * S + s)) * H + slice * 64;
      float acc = 0.f;
      for (int i = 0; i < 64; i++)
        acc += sVa[slice * 64 + i] * tanhf(sQ[slice * 64 + i] + uk[i]);
      red[s][slice] = acc;
      __syncthreads();
      if (tid < 64) {
        float sc = va_b;
#pragma unroll
        for (int i = 0; i < 8; i++) sc += red[tid][i];
        sSc[tid] = sc;
      }
      __syncthreads();
      if (tid < 64) {
        float v = sSc[tid];
        float m = v;
        for (int o = 32; o; o >>= 1) m = fmaxf(m, __shfl_xor(m, o, 64));
        float e = expf(v - m);
        float sum = e;
        for (int o = 32; o; o >>= 1) sum += __shfl_xor(sum, o, 64);
        float wt = e / sum;
        sSc[tid] = wt;
        if ((tid >> 3) == sl)
          attn_out[((size_t)bb * T + t) * S + tid] = wt;
      }
      __syncthreads();
      int hl = tid & 63, chunk = tid >> 6;
      const float* kb = keys + ((size_t)bb * S) * H + sl * 64 + hl;
      float acc2 = 0.f;
      for (int s2 = chunk * 8; s2 < chunk * 8 + 8; s2++)
        acc2 += sSc[s2] * kb[(size_t)s2 * H];
      red[hl][chunk] = acc2;
      __syncthreads();
      if (tid < 64) {
        float s3 = 0.f;
#pragma unroll
        for (int i = 0; i < 8; i++) s3 += red[tid][i];
        CTX[bb * H + sl * 64 + tid] = s3;
      }
    }
    gridbar(bar, gridDim.x);
    // ---- Phase B: gates + GRU update for jh in {jh0, jh0+1}, all b ----
    {
      int c = tid >> 3, slice = tid & 7;  // c = b*2+lj
      int b = c >> 1, lj = c & 1;
      const float* xsrc = (slice < 4) ? (CTX + b * H + slice * 128)
                                      : (hcur + b * H + (slice - 4) * 128);
      const float* w0 = &sWcat[lj * 3 + 0][slice * 128];
      const float* w1 = &sWcat[lj * 3 + 1][slice * 128];
      const float* w2 = &sWcat[lj * 3 + 2][slice * 128];
      float a0 = 0.f, a1 = 0.f, a2 = 0.f;
#pragma unroll 8
      for (int i = 0; i < 128; i += 4) {
        float4 x4 = *(const float4*)&xsrc[i];
        a0 += x4.x * w0[i] + x4.y * w0[i + 1] + x4.z * w0[i + 2] + x4.w * w0[i + 3];
        a1 += x4.x * w1[i] + x4.y * w1[i + 1] + x4.z * w1[i + 2] + x4.w * w1[i + 3];
        a2 += x4.x * w2[i] + x4.y * w2[i + 1] + x4.z * w2[i + 2] + x4.w * w2[i + 3];
      }
      red3[0][c][slice] = a0; red3[1][c][slice] = a1; red3[2][c][slice] = a2;
      __syncthreads();
      if (tid < 64) {
        int b2 = tid >> 1, lj2 = tid & 1;
        int jh = jh0 + lj2;
        float ic[3], hh[3];
#pragma unroll
        for (int g = 0; g < 3; g++) {
          ic[g] = red3[g][tid][0] + red3[g][tid][1] + red3[g][tid][2] + red3[g][tid][3];
          hh[g] = red3[g][tid][4] + red3[g][tid][5] + red3[g][tid][6] + red3[g][tid][7];
        }
        size_t gbase = ((size_t)b2 * T + t) * G3 + jh;
        float gi0 = GIE[gbase + 0 * H] + ic[0];
        float gi1 = GIE[gbase + 1 * H] + ic[1];
        float gi2 = GIE[gbase + 2 * H] + ic[2];
        float gh0 = hh[0] + b_hh[0 * H + jh];
        float gh1 = hh[1] + b_hh[1 * H + jh];
        float gh2 = hh[2] + b_hh[2 * H + jh];
        float r = 1.f / (1.f + expf(-(gi0 + gh0)));
        float z = 1.f / (1.f + expf(-(gi1 + gh1)));
        float n = tanhf(gi2 + r * gh2);
        float hold = hcur[b2 * H + jh];
        float hn = (1.f - z) * n + z * hold;
        HALL[(size_t)(t + 1) * B * H + b2 * H + jh] = hn;
        HBF[((size_t)b2 * T + t) * H + jh] = __float2bfloat16(hn);
      }
    }
    gridbar(bar, gridDim.x);
  }
}

// -------------------- bf16 MFMA out-projection: [2048,512] x [32000,512]^T --------------------
__global__ __launch_bounds__(256) void k_outgemm(
    const __hip_bfloat16* __restrict__ Abf, const __hip_bfloat16* __restrict__ Bbf,
    const float* __restrict__ bias, float* __restrict__ Cmat) {
  constexpr int LDT = 40;  // bf16 row stride (80B, 16B aligned)
  __shared__ __align__(16) short As[128 * LDT];
  __shared__ __align__(16) short Bs[128 * LDT];
  int bm = blockIdx.y, bn = blockIdx.x;
  int tid = threadIdx.x;
  int lane = tid & 63, wid = tid >> 6;
  int wm = wid >> 1, wn = wid & 1;
  f32x4 acc[4][4] = {};
  int srow = tid >> 1, shalf = tid & 1;
  for (int k0 = 0; k0 < 512; k0 += 32) {
    const float4* ga = (const float4*)&Abf[(size_t)(bm * 128 + srow) * 512 + k0 + shalf * 16];
    const float4* gb = (const float4*)&Bbf[(size_t)(bn * 128 + srow) * 512 + k0 + shalf * 16];
    float4 va0 = ga[0], va1 = ga[1];
    float4 vb0 = gb[0], vb1 = gb[1];
    __syncthreads();
    *(float4*)&As[srow * LDT + shalf * 16] = va0;
    *(float4*)&As[srow * LDT + shalf * 16 + 8] = va1;
    *(float4*)&Bs[srow * LDT + shalf * 16] = vb0;
    *(float4*)&Bs[srow * LDT + shalf * 16 + 8] = vb1;
    __syncthreads();
    int kc = lane >> 4, rl = lane & 15;
    bf16x8 af[4], bfv[4];
#pragma unroll
    for (int f = 0; f < 4; f++) {
      af[f] = *(const bf16x8*)&As[(wm * 64 + f * 16 + rl) * LDT + kc * 8];
      bfv[f] = *(const bf16x8*)&Bs[(wn * 64 + f * 16 + rl) * LDT + kc * 8];
    }
#pragma unroll
    for (int i = 0; i < 4; i++)
#pragma unroll
      for (int j = 0; j < 4; j++)
        acc[i][j] = __builtin_amdgcn_mfma_f32_16x16x32_bf16(af[i], bfv[j], acc[i][j], 0, 0, 0);
  }
  int cl = lane & 15, rg = lane >> 4;
#pragma unroll
  for (int i = 0; i < 4; i++) {
    int m = bm * 128 + wm * 64 + i * 16 + rg * 4;
#pragma unroll
    for (int j = 0; j < 4; j++) {
      int n = bn * 128 + wn * 64 + j * 16 + cl;
      float bv = bias[n];
#pragma unroll
      for (int r = 0; r < 4; r++)
        Cmat[(size_t)(m + r) * V + n] = acc[i][j][r] + bv;
    }
  }
}

// -------------------- in-place log_softmax over rows of 32000 --------------------
__global__ __launch_bounds__(256) void k_logsoftmax(float* __restrict__ Cmat) {
  int row = blockIdx.x;
  float* p = Cmat + (size_t)row * V;
  int tid = threadIdx.x;
  __shared__ float sred[4];
  float m = -INFINITY;
  for (int i = tid * 4; i < V; i += 1024) {
    float4 v = *(const float4*)&p[i];
    m = fmaxf(m, fmaxf(fmaxf(v.x, v.y), fmaxf(v.z, v.w)));
  }
  for (int o = 32; o; o >>= 1) m = fmaxf(m, __shfl_xor(m, o, 64));
  if ((tid & 63) == 0) sred[tid >> 6] = m;
  __syncthreads();
  m = fmaxf(fmaxf(sred[0], sred[1]), fmaxf(sred[2], sred[3]));
  float sum = 0.f;
  for (int i = tid * 4; i < V; i += 1024) {
    float4 v = *(const float4*)&p[i];
    sum += expf(v.x - m) + expf(v.y - m) + expf(v.z - m) + expf(v.w - m);
  }
  for (int o = 32; o; o >>= 1) sum += __shfl_xor(sum, o, 64);
  __syncthreads();
  if ((tid & 63) == 0) sred[tid >> 6] = sum;
  __syncthreads();
  float lse = m + logf(sred[0] + sred[1] + sred[2] + sred[3]);
  for (int i = tid * 4; i < V; i += 1024) {
    float4 v = *(const float4*)&p[i];
    v.x -= lse; v.y -= lse; v.z -= lse; v.w -= lse;
    *(float4*)&p[i] = v;
  }
}

__global__ void k_copy_ht(const float* __restrict__ hsrc, float* __restrict__ o) {
  int i = blockIdx.x * 256 + threadIdx.x;
  if (i < B * H) o[i] = hsrc[i];
}

extern "C" void kernel_launch(void* const* d_in, const int* in_sizes, int n_in,
                              void* d_out, int out_size, void* d_ws, size_t ws_size,
                              hipStream_t stream) {
  (void)in_sizes; (void)n_in; (void)out_size; (void)ws_size;
  const float* keys = (const float*)d_in[0];
  const float* ehid = (const float*)d_in[1];
  const int* tgt    = (const int*)d_in[2];
  const float* emb  = (const float*)d_in[4];
  const float* Wa_w = (const float*)d_in[5];
  const float* Wa_b = (const float*)d_in[6];
  const float* Ua_w = (const float*)d_in[7];
  const float* Ua_b = (const float*)d_in[8];
  const float* Va_w = (const float*)d_in[9];
  const float* Va_b = (const float*)d_in[10];
  const float* W_ih = (const float*)d_in[11];
  const float* W_hh = (const float*)d_in[12];
  const float* b_ih = (const float*)d_in[13];
  const float* b_hh = (const float*)d_in[14];
  const float* out_w = (const float*)d_in[15];
  const float* out_b = (const float*)d_in[16];
  float* ws = (float*)d_ws;
  float* out = (float*)d_out;
  float* logits = out;                              // [B,T,V]
  float* ht_out = out + (size_t)B * T * V;          // [1,B,H]
  float* attn_out = ht_out + (size_t)B * H;         // [B,T,S]

  hipLaunchKernelGGL(k_init, dim3(64), dim3(256), 0, stream, ehid, tgt, ws);
  hipLaunchKernelGGL(k_conv_outw, dim3((V * H / 4 + 255) / 256), dim3(256), 0, stream,
                     out_w, (ushort*)(ws + OWBF_OFF), V * H / 4);
  // Ua_keys = keys @ Ua_w.T + Ua_b
  hipLaunchKernelGGL(k_gemm_at, dim3(32, 8), dim3(256), 0, stream,
                     keys, Ua_w, 512, Ua_b, ws + UAK_OFF, (const int*)nullptr, 512);
  // Gi_e = emb[tokens] @ W_ih[:, :512].T + b_ih
  hipLaunchKernelGGL(k_gemm_at, dim3(32, 24), dim3(256), 0, stream,
                     emb, W_ih, 1024, b_ih, ws + GIE_OFF, (const int*)(ws + ROWIDX_OFF), G3);
  hipLaunchKernelGGL(k_recur, dim3(256), dim3(512), 0, stream,
                     keys, Wa_w, Wa_b, Va_w, Va_b, W_ih, W_hh, b_hh, ws, attn_out);
  hipLaunchKernelGGL(k_outgemm, dim3(250, 16), dim3(256), 0, stream,
                     (const __hip_bfloat16*)(ws + HBF_OFF),
                     (const __hip_bfloat16*)(ws + OWBF_OFF), out_b, logits);
  hipLaunchKernelGGL(k_logsoftmax, dim3(BT), dim3(256), 0, stream, logits);
  hipLaunchKernelGGL(k_copy_ht, dim3(64), dim3(256), 0, stream,
                     ws + HALL_OFF + (size_t)T * B * H, ht_out);
}

// Round 2
// 3090.368 us; speedup vs baseline: 3.5119x; 3.5119x over previous
//
#include <hip/hip_runtime.h>
#include <hip/hip_bf16.h>
#include <math.h>

constexpr int B = 32, S = 64, T = 64, H = 512, V = 32000;
constexpr int G3 = 3 * H;     // 1536
constexpr int BT = B * T;     // 2048

// ---- workspace layout (float offsets) ----
constexpr size_t UAK_OFF    = 0;          // [B*S*H]     1,048,576
constexpr size_t GIE_OFF    = 1048576;    // [B*T*G3]    3,145,728
constexpr size_t KWT_OFF    = 4194304;    // [B*G3*S]    3,145,728
constexpr size_t HALL_OFF   = 7340032;    // [(T+1)*B*H] 1,064,960
constexpr size_t SCP_OFF    = 8404992;    // [8*B*S]     16,384
constexpr size_t ROWIDX_OFF = 8421376;    // 2048 ints
constexpr size_t HBF_OFF    = 8423424;    // bf16 [B*T*H] = 524,288 float slots
constexpr size_t OWBF_OFF   = 0;          // bf16 [V*H] = 8,192,000 float slots,
                                          // ALIASES UAK/GIE/KWT/HALL (all dead by then)

typedef __attribute__((ext_vector_type(8))) short bf16x8;
typedef __attribute__((ext_vector_type(4))) float f32x4;

// -------------------- init: h0, token row indices --------------------
__global__ void k_init(const float* __restrict__ eh, const int* __restrict__ tgt,
                       float* __restrict__ ws) {
  int i = blockIdx.x * 256 + threadIdx.x;      // grid 64*256 = 16384
  if (i < B * H) ws[HALL_OFF + i] = eh[i];
  if (i < BT) {
    int b = i / T, t = i % T;
    ((int*)(ws + ROWIDX_OFF))[i] = (t == 0) ? 0 : tgt[b * T + t - 1];
  }
}

// -------------------- out_w fp32 -> bf16 (runs AFTER recurrence; aliases ws) ----
__global__ void k_conv_outw(const float* __restrict__ w, ushort* __restrict__ o, int n4) {
  int i = blockIdx.x * blockDim.x + threadIdx.x;
  if (i < n4) {
    float4 v = *(const float4*)&w[(size_t)i * 4];
    ushort4 u;
    __hip_bfloat16 h0 = __float2bfloat16(v.x); u.x = *(ushort*)&h0;
    __hip_bfloat16 h1 = __float2bfloat16(v.y); u.y = *(ushort*)&h1;
    __hip_bfloat16 h2 = __float2bfloat16(v.z); u.z = *(ushort*)&h2;
    __hip_bfloat16 h3 = __float2bfloat16(v.w); u.w = *(ushort*)&h3;
    *(ushort4*)&o[(size_t)i * 4] = u;
  }
}

// -------- fp32 tiled GEMM: C[m,n] = A[arow(m),0:512] . Bw[n*ldb+koff...] + bias[n] --------
__global__ __launch_bounds__(256) void k_gemm_at(
    const float* __restrict__ A, const float* __restrict__ Bw, int ldb,
    const float* __restrict__ bias, float* __restrict__ C,
    const int* __restrict__ rowidx, int N) {
  __shared__ float As[64][36];
  __shared__ float Bs[64][36];
  int tid = threadIdx.x;
  int bm = blockIdx.x, bn = blockIdx.y;
  int tr = tid >> 4, tc = tid & 15;
  float acc[4][4] = {};
  for (int k0 = 0; k0 < 512; k0 += 32) {
    __syncthreads();
#pragma unroll
    for (int i = 0; i < 2; i++) {
      int e = tid + i * 256;
      int row = e >> 3, c4 = (e & 7) * 4;
      int ar = bm * 64 + row;
      int arow = rowidx ? rowidx[ar] : ar;
      *(float4*)&As[row][c4] = *(const float4*)&A[(size_t)arow * 512 + k0 + c4];
      int br = bn * 64 + row;
      *(float4*)&Bs[row][c4] = *(const float4*)&Bw[(size_t)br * ldb + k0 + c4];
    }
    __syncthreads();
#pragma unroll
    for (int kk = 0; kk < 32; kk++) {
      float av[4], bv[4];
#pragma unroll
      for (int i = 0; i < 4; i++) av[i] = As[tr * 4 + i][kk];
#pragma unroll
      for (int j = 0; j < 4; j++) bv[j] = Bs[tc * 4 + j][kk];
#pragma unroll
      for (int i = 0; i < 4; i++)
#pragma unroll
        for (int j = 0; j < 4; j++) acc[i][j] += av[i] * bv[j];
    }
  }
#pragma unroll
  for (int i = 0; i < 4; i++) {
    int m = bm * 64 + tr * 4 + i;
#pragma unroll
    for (int j = 0; j < 4; j++) {
      int n = bn * 64 + tc * 4 + j;
      C[(size_t)m * N + n] = acc[i][j] + bias[n];
    }
  }
}

// -------- KWT[b, col, s] = sum_k W_ih[col, 512+k] * keys[b*64+s, k] --------
__global__ __launch_bounds__(256) void k_gemm_kwt(
    const float* __restrict__ W_ih, const float* __restrict__ keys,
    float* __restrict__ KWT) {
  __shared__ float As[64][36];
  __shared__ float Bs[64][36];
  int tid = threadIdx.x;
  int bm = blockIdx.x, b = blockIdx.y;
  int tr = tid >> 4, tc = tid & 15;
  float acc[4][4] = {};
  for (int k0 = 0; k0 < 512; k0 += 32) {
    __syncthreads();
#pragma unroll
    for (int i = 0; i < 2; i++) {
      int e = tid + i * 256;
      int row = e >> 3, c4 = (e & 7) * 4;
      *(float4*)&As[row][c4] = *(const float4*)&W_ih[(size_t)(bm * 64 + row) * 1024 + 512 + k0 + c4];
      *(float4*)&Bs[row][c4] = *(const float4*)&keys[(size_t)(b * 64 + row) * 512 + k0 + c4];
    }
    __syncthreads();
#pragma unroll
    for (int kk = 0; kk < 32; kk++) {
      float av[4], bv[4];
#pragma unroll
      for (int i = 0; i < 4; i++) av[i] = As[tr * 4 + i][kk];
#pragma unroll
      for (int j = 0; j < 4; j++) bv[j] = Bs[tc * 4 + j][kk];
#pragma unroll
      for (int i = 0; i < 4; i++)
#pragma unroll
        for (int j = 0; j < 4; j++) acc[i][j] += av[i] * bv[j];
    }
  }
#pragma unroll
  for (int i = 0; i < 4; i++) {
    int m = bm * 64 + tr * 4 + i;
#pragma unroll
    for (int j = 0; j < 4; j++)
      KWT[((size_t)b * G3 + m) * S + tc * 4 + j] = acc[i][j];
  }
}

// -------------------- step phase A: q + partial scores --------------------
// grid 256 = (b=bid>>3, g=bid&7), 256 threads. Writes SCP[g][b*64+s].
__global__ __launch_bounds__(256) void k_la(
    const float* __restrict__ Wa_w, const float* __restrict__ Wa_b,
    const float* __restrict__ Va_w, const float* __restrict__ Va_b,
    float* __restrict__ ws, int t) {
  const int bid = blockIdx.x;
  const int b = bid >> 3, g = bid & 7;
  const int tid = threadIdx.x;
  const float* h = ws + HALL_OFF + (size_t)t * B * H + b * H;
  const float* UAK = ws + UAK_OFF + (size_t)b * S * H;
  float* SCP = ws + SCP_OFF;
  __shared__ float qp[64][4];
  __shared__ float qs[64];
  __shared__ float vs[64];
  __shared__ float sp[64][5];
  if (tid < 64) vs[tid] = Va_w[g * 64 + tid];
  // q[b, g*64+j] partial over k-quarter kq
  int j = tid >> 2, kq = tid & 3;
  {
    const float* hv = h + kq * 128;
    const float* wv = Wa_w + (size_t)(g * 64 + j) * H + kq * 128;
    float acc = 0.f;
#pragma unroll
    for (int i = 0; i < 128; i += 4) {
      float4 a4 = *(const float4*)&hv[i];
      float4 w4 = *(const float4*)&wv[i];
      acc += a4.x * w4.x + a4.y * w4.y + a4.z * w4.z + a4.w * w4.w;
    }
    qp[j][kq] = acc;
  }
  __syncthreads();
  if (tid < 64)
    qs[tid] = qp[tid][0] + qp[tid][1] + qp[tid][2] + qp[tid][3] + Wa_b[g * 64 + tid];
  __syncthreads();
  // partial score over this WG's 64-j slice
  int s = tid >> 2, jc = tid & 3;
  {
    const float* uk = UAK + (size_t)s * H + g * 64 + jc * 16;
    float ps = 0.f;
#pragma unroll
    for (int i = 0; i < 16; i++)
      ps += vs[jc * 16 + i] * tanhf(qs[jc * 16 + i] + uk[i]);
    sp[s][jc] = ps;
  }
  __syncthreads();
  if (tid < 64) {
    float v = sp[tid][0] + sp[tid][1] + sp[tid][2] + sp[tid][3];
    if (g == 0) v += Va_b[0];
    SCP[g * BT + b * 64 + tid] = v;
  }
}

// -------------------- step phase B: softmax + gates + h update --------------------
// grid 256 WGs (w -> h cols {2w,2w+1}), 256 threads.
__global__ __launch_bounds__(256) void k_lb(
    const float* __restrict__ W_hh, const float* __restrict__ b_hh,
    float* __restrict__ ws, float* __restrict__ attn_out, int t) {
  const int w = blockIdx.x;
  const int tid = threadIdx.x;
  const int jh0 = 2 * w;
  const float* SCP = ws + SCP_OFF;
  const float* KWT = ws + KWT_OFF;
  const float* GIE = ws + GIE_OFF;
  const float* hcur = ws + HALL_OFF + (size_t)t * B * H;
  float* hnext = ws + HALL_OFF + (size_t)(t + 1) * B * H;
  __hip_bfloat16* HBF = (__hip_bfloat16*)(ws + HBF_OFF);
  __shared__ float sw[32][64];
  __shared__ float ga[32][2][4];
  // 1. reduce the 8 partial-score slices (fixed order -> deterministic)
  for (int i = tid; i < BT; i += 256) {
    float v = 0.f;
#pragma unroll
    for (int g = 0; g < 8; g++) v += SCP[g * BT + i];
    sw[i >> 6][i & 63] = v;
  }
  __syncthreads();
  // 2. row softmax: 4 waves x 8 rows
  {
    int lane = tid & 63, wv = tid >> 6;
    for (int b = wv * 8; b < wv * 8 + 8; b++) {
      float v = sw[b][lane];
      float m = v;
      for (int o = 32; o; o >>= 1) m = fmaxf(m, __shfl_xor(m, o, 64));
      float e = expf(v - m);
      float su = e;
      for (int o = 32; o; o >>= 1) su += __shfl_xor(su, o, 64);
      sw[b][lane] = e / su;
    }
  }
  __syncthreads();
  if (w < 32 && tid < 64)
    attn_out[((size_t)w * T + t) * S + tid] = sw[w][tid];
  // 3. gates: thread t<192 -> (b, c); c -> (g=c>>1, lj=c&1)
  if (tid < 192) {
    int b = tid / 6, c = tid % 6;
    int g = c >> 1, lj = c & 1;
    int col = g * 512 + jh0 + lj;
    const float* kw = KWT + ((size_t)b * G3 + col) * S;
    float gic = 0.f;
#pragma unroll
    for (int s4 = 0; s4 < 64; s4 += 4) {
      float4 k4 = *(const float4*)&kw[s4];
      gic += k4.x * sw[b][s4] + k4.y * sw[b][s4 + 1] + k4.z * sw[b][s4 + 2] + k4.w * sw[b][s4 + 3];
    }
    const float* wr = W_hh + (size_t)col * H;
    const float* hb = hcur + b * H;
    float gh = 0.f;
    for (int k = 0; k < 512; k += 4) {
      float4 w4 = *(const float4*)&wr[k];
      float4 h4 = *(const float4*)&hb[k];
      gh += w4.x * h4.x + w4.y * h4.y + w4.z * h4.z + w4.w * h4.w;
    }
    gh += b_hh[col];
    float gi = GIE[((size_t)b * T + t) * G3 + col] + gic;
    if (g == 2) { ga[b][lj][2] = gi; ga[b][lj][3] = gh; }
    else ga[b][lj][g] = gi + gh;
  }
  __syncthreads();
  // 4. GRU update for the 64 (b, lj) outputs
  if (tid < 64) {
    int b = tid >> 1, lj = tid & 1;
    float r = 1.f / (1.f + expf(-ga[b][lj][0]));
    float z = 1.f / (1.f + expf(-ga[b][lj][1]));
    float n = tanhf(ga[b][lj][2] + r * ga[b][lj][3]);
    float hold = hcur[b * H + jh0 + lj];
    float hn = (1.f - z) * n + z * hold;
    hnext[b * H + jh0 + lj] = hn;
    HBF[((size_t)b * T + t) * H + jh0 + lj] = __float2bfloat16(hn);
  }
}

// -------------------- bf16 MFMA out-projection: [2048,512] x [32000,512]^T --------------------
__global__ __launch_bounds__(256) void k_outgemm(
    const __hip_bfloat16* __restrict__ Abf, const __hip_bfloat16* __restrict__ Bbf,
    const float* __restrict__ bias, float* __restrict__ Cmat) {
  constexpr int LDT = 40;
  __shared__ __align__(16) short As[128 * LDT];
  __shared__ __align__(16) short Bs[128 * LDT];
  int bm = blockIdx.y, bn = blockIdx.x;
  int tid = threadIdx.x;
  int lane = tid & 63, wid = tid >> 6;
  int wm = wid >> 1, wn = wid & 1;
  f32x4 acc[4][4] = {};
  int srow = tid >> 1, shalf = tid & 1;
  for (int k0 = 0; k0 < 512; k0 += 32) {
    const float4* ga = (const float4*)&Abf[(size_t)(bm * 128 + srow) * 512 + k0 + shalf * 16];
    const float4* gb = (const float4*)&Bbf[(size_t)(bn * 128 + srow) * 512 + k0 + shalf * 16];
    float4 va0 = ga[0], va1 = ga[1];
    float4 vb0 = gb[0], vb1 = gb[1];
    __syncthreads();
    *(float4*)&As[srow * LDT + shalf * 16] = va0;
    *(float4*)&As[srow * LDT + shalf * 16 + 8] = va1;
    *(float4*)&Bs[srow * LDT + shalf * 16] = vb0;
    *(float4*)&Bs[srow * LDT + shalf * 16 + 8] = vb1;
    __syncthreads();
    int kc = lane >> 4, rl = lane & 15;
    bf16x8 af[4], bfv[4];
#pragma unroll
    for (int f = 0; f < 4; f++) {
      af[f] = *(const bf16x8*)&As[(wm * 64 + f * 16 + rl) * LDT + kc * 8];
      bfv[f] = *(const bf16x8*)&Bs[(wn * 64 + f * 16 + rl) * LDT + kc * 8];
    }
#pragma unroll
    for (int i = 0; i < 4; i++)
#pragma unroll
      for (int j = 0; j < 4; j++)
        acc[i][j] = __builtin_amdgcn_mfma_f32_16x16x32_bf16(af[i], bfv[j], acc[i][j], 0, 0, 0);
  }
  int cl = lane & 15, rg = lane >> 4;
#pragma unroll
  for (int i = 0; i < 4; i++) {
    int m = bm * 128 + wm * 64 + i * 16 + rg * 4;
#pragma unroll
    for (int j = 0; j < 4; j++) {
      int n = bn * 128 + wn * 64 + j * 16 + cl;
      float bv = bias[n];
#pragma unroll
      for (int r = 0; r < 4; r++)
        Cmat[(size_t)(m + r) * V + n] = acc[i][j][r] + bv;
    }
  }
}

// -------------------- in-place log_softmax over rows of 32000 --------------------
__global__ __launch_bounds__(256) void k_logsoftmax(float* __restrict__ Cmat) {
  int row = blockIdx.x;
  float* p = Cmat + (size_t)row * V;
  int tid = threadIdx.x;
  __shared__ float sred[4];
  float m = -INFINITY;
  for (int i = tid * 4; i < V; i += 1024) {
    float4 v = *(const float4*)&p[i];
    m = fmaxf(m, fmaxf(fmaxf(v.x, v.y), fmaxf(v.z, v.w)));
  }
  for (int o = 32; o; o >>= 1) m = fmaxf(m, __shfl_xor(m, o, 64));
  if ((tid & 63) == 0) sred[tid >> 6] = m;
  __syncthreads();
  m = fmaxf(fmaxf(sred[0], sred[1]), fmaxf(sred[2], sred[3]));
  float sum = 0.f;
  for (int i = tid * 4; i < V; i += 1024) {
    float4 v = *(const float4*)&p[i];
    sum += expf(v.x - m) + expf(v.y - m) + expf(v.z - m) + expf(v.w - m);
  }
  for (int o = 32; o; o >>= 1) sum += __shfl_xor(sum, o, 64);
  __syncthreads();
  if ((tid & 63) == 0) sred[tid >> 6] = sum;
  __syncthreads();
  float lse = m + logf(sred[0] + sred[1] + sred[2] + sred[3]);
  for (int i = tid * 4; i < V; i += 1024) {
    float4 v = *(const float4*)&p[i];
    v.x -= lse; v.y -= lse; v.z -= lse; v.w -= lse;
    *(float4*)&p[i] = v;
  }
}

__global__ void k_copy_ht(const float* __restrict__ hsrc, float* __restrict__ o) {
  int i = blockIdx.x * 256 + threadIdx.x;
  if (i < B * H) o[i] = hsrc[i];
}

extern "C" void kernel_launch(void* const* d_in, const int* in_sizes, int n_in,
                              void* d_out, int out_size, void* d_ws, size_t ws_size,
                              hipStream_t stream) {
  (void)in_sizes; (void)n_in; (void)out_size; (void)ws_size;
  const float* keys = (const float*)d_in[0];
  const float* ehid = (const float*)d_in[1];
  const int* tgt    = (const int*)d_in[2];
  const float* emb  = (const float*)d_in[4];
  const float* Wa_w = (const float*)d_in[5];
  const float* Wa_b = (const float*)d_in[6];
  const float* Ua_w = (const float*)d_in[7];
  const float* Ua_b = (const float*)d_in[8];
  const float* Va_w = (const float*)d_in[9];
  const float* Va_b = (const float*)d_in[10];
  const float* W_ih = (const float*)d_in[11];
  const float* W_hh = (const float*)d_in[12];
  const float* b_ih = (const float*)d_in[13];
  const float* b_hh = (const float*)d_in[14];
  const float* out_w = (const float*)d_in[15];
  const float* out_b = (const float*)d_in[16];
  float* ws = (float*)d_ws;
  float* out = (float*)d_out;
  float* logits = out;                              // [B,T,V]
  float* ht_out = out + (size_t)B * T * V;          // [1,B,H]
  float* attn_out = ht_out + (size_t)B * H;         // [B,T,S]

  hipLaunchKernelGGL(k_init, dim3(64), dim3(256), 0, stream, ehid, tgt, ws);
  // Ua_keys = keys @ Ua_w.T + Ua_b
  hipLaunchKernelGGL(k_gemm_at, dim3(32, 8), dim3(256), 0, stream,
                     keys, Ua_w, 512, Ua_b, ws + UAK_OFF, (const int*)nullptr, 512);
  // Gi_e = emb[tokens] @ W_ih[:, :512].T + b_ih
  hipLaunchKernelGGL(k_gemm_at, dim3(32, 24), dim3(256), 0, stream,
                     emb, W_ih, 1024, b_ih, ws + GIE_OFF, (const int*)(ws + ROWIDX_OFF), G3);
  // KWT[b,col,s] = W_ih_ctx @ keys[b]^T
  hipLaunchKernelGGL(k_gemm_kwt, dim3(24, 32), dim3(256), 0, stream,
                     W_ih, keys, ws + KWT_OFF);
  // serial recurrence: 2 small launches per step (launch boundary = barrier)
  for (int t = 0; t < T; t++) {
    hipLaunchKernelGGL(k_la, dim3(256), dim3(256), 0, stream,
                       Wa_w, Wa_b, Va_w, Va_b, ws, t);
    hipLaunchKernelGGL(k_lb, dim3(256), dim3(256), 0, stream,
                       W_hh, b_hh, ws, attn_out, t);
  }
  hipLaunchKernelGGL(k_copy_ht, dim3(64), dim3(256), 0, stream,
                     ws + HALL_OFF + (size_t)T * B * H, ht_out);
  // bf16 out_w copy goes into the (now dead) precompute region
  hipLaunchKernelGGL(k_conv_outw, dim3((V * H / 4 + 255) / 256), dim3(256), 0, stream,
                     out_w, (ushort*)(ws + OWBF_OFF), V * H / 4);
  hipLaunchKernelGGL(k_outgemm, dim3(250, 16), dim3(256), 0, stream,
                     (const __hip_bfloat16*)(ws + HBF_OFF),
                     (const __hip_bfloat16*)(ws + OWBF_OFF), out_b, logits);
  hipLaunchKernelGGL(k_logsoftmax, dim3(BT), dim3(256), 0, stream, logits);
}